// Round 5
// baseline (306.914 us; speedup 1.0000x reference)
//
#include <hip/hip_runtime.h>
#include <math.h>

#define EMB 256
#define DR  128   // resource feature dim
#define DO  192   // operation feature dim
#define DE  64    // edge_attr dim
#define RPB 8     // resources per block in k_h part
#define FRPB 32   // resources per block in k_final
#define KV_CH 8   // k-rows per block in the v part of k_prep
#define HB 256    // histogram blocks in k_prep
#define GCH 64    // edges staged per chunk in k_gather

__device__ __forceinline__ float leaky(float x) { return x >= 0.f ? x : 0.2f * x; }

// Fused prep: blocks [0,128) transpose W_self -> wsT [128][256];
// blocks [128,384) transpose W_op -> wT [256][256];
// blocks [384,416) accumulate v[j] = sum_k W_op[k][j]*a_op[256+k] (v pre-zeroed);
// blocks [416,416+HB) histogram edge_dst into counts (pre-zeroed).
__global__ void k_prep(float* __restrict__ wsT, float* __restrict__ wT,
                       float* __restrict__ v, const float* __restrict__ W_self,
                       const float* __restrict__ W_op, const float* __restrict__ a_op,
                       const int* __restrict__ edst, int* __restrict__ counts, int E) {
    int b = blockIdx.x, t = threadIdx.x;
    if (b < 128) {
        int i = b * 256 + t;
        int k = i & 255, j = i >> 8;    // wsT[j*256+k] = W_self[k*128+j]
        wsT[i] = W_self[k * DR + j];
    } else if (b < 384) {
        int i = (b - 128) * 256 + t;
        int k = i & 255, j = i >> 8;    // wT[j*256+k] = W_op[k*256+j]
        wT[i] = W_op[(size_t)k * EMB + j];
    } else if (b < 416) {
        int k0 = (b - 384) * KV_CH;
        float acc = 0.f;
#pragma unroll
        for (int u = 0; u < KV_CH; u++)
            acc += W_op[(size_t)(k0 + u) * EMB + t] * a_op[EMB + k0 + u];
        atomicAdd(&v[t], acc);
    } else {
        int i = (b - 416) * 256 + t;
        int n = HB * 256;
        for (int e = i; e < E; e += n) atomicAdd(&counts[edst[e]], 1);
    }
}

// Fused: blocks [0,NBH): h[r] = resources[r] @ wsT, plus per-resource scores
// tcross[r] = h[r]·a_op[:256], p_self[r] = exp(leaky(h[r]·(a_self[:256]+a_self[256:]))).
// blocks [NBH, ...): s_op[o] = operations[o][0:192]·v[0:192].
__global__ void k_hs(const float* __restrict__ res, const float* __restrict__ wsT,
                     const float* __restrict__ a_self, const float* __restrict__ a_op,
                     const float* __restrict__ ops, const float* __restrict__ v,
                     float* __restrict__ h, float* __restrict__ tcross,
                     float* __restrict__ p_self, float* __restrict__ s_op,
                     int R, int O, int NBH) {
    if ((int)blockIdx.x < NBH) {
        __shared__ float rrow[RPB][DR];
        __shared__ float hred[RPB][4][2];
        int r0 = blockIdx.x * RPB;
        int k = threadIdx.x;
        int w = k >> 6, l = k & 63;
        for (int i = k; i < RPB * DR; i += EMB) {
            int rr = i / DR, j = i % DR;
            rrow[rr][j] = (r0 + rr < R) ? res[(size_t)(r0 + rr) * DR + j] : 0.f;
        }
        __syncthreads();
        float acc[RPB];
#pragma unroll
        for (int rr = 0; rr < RPB; rr++) acc[rr] = 0.f;
        for (int j = 0; j < DR; j++) {
            float wv = wsT[j * EMB + k];
#pragma unroll
            for (int rr = 0; rr < RPB; rr++) acc[rr] += rrow[rr][j] * wv;
        }
        float as_ = a_self[k] + a_self[EMB + k];
        float ao_ = a_op[k];
#pragma unroll
        for (int rr = 0; rr < RPB; rr++) {
            if (r0 + rr < R) h[(size_t)(r0 + rr) * EMB + k] = acc[rr];
            float s1 = acc[rr] * as_;
            float s2 = acc[rr] * ao_;
            for (int m = 1; m < 64; m <<= 1) {
                s1 += __shfl_xor(s1, m, 64);
                s2 += __shfl_xor(s2, m, 64);
            }
            if (l == 0) { hred[rr][w][0] = s1; hred[rr][w][1] = s2; }
        }
        __syncthreads();
        if (k < RPB) {
            int r = r0 + k;
            if (r < R) {
                float a1 = hred[k][0][0] + hred[k][1][0] + hred[k][2][0] + hred[k][3][0];
                float a2 = hred[k][0][1] + hred[k][1][1] + hred[k][2][1] + hred[k][3][1];
                p_self[r] = expf(leaky(a1));
                tcross[r] = a2;
            }
        }
    } else {
        __shared__ float vv[DO];
        int tid = threadIdx.x;
        if (tid < DO) vv[tid] = v[tid];
        __syncthreads();
        int wave = tid >> 6, lane = tid & 63;
        int o = (blockIdx.x - NBH) * 4 + wave;
        if (o >= O) return;
        const float* row = ops + (size_t)o * DO;
        float acc = row[lane] * vv[lane] + row[lane + 64] * vv[lane + 64] +
                    row[lane + 128] * vv[lane + 128];
        for (int m = 1; m < 64; m <<= 1) acc += __shfl_xor(acc, m, 64);
        if (lane == 0) s_op[o] = acc;
    }
}

// single block: exclusive scan of counts -> offs (R+1) and cursor copy.
__global__ void k_scan(const int* __restrict__ counts, int* __restrict__ offs,
                       int* __restrict__ cursor, int R) {
    __shared__ int ps[1024];
    int tid = threadIdx.x;
    int chunk = (R + 1023) >> 10;
    int start = tid * chunk;
    int end = min(start + chunk, R);
    int s = 0;
    for (int i = start; i < end; i++) s += counts[i];
    ps[tid] = s;
    __syncthreads();
    for (int off = 1; off < 1024; off <<= 1) {
        int add = (tid >= off) ? ps[tid - off] : 0;
        __syncthreads();
        ps[tid] += add;
        __syncthreads();
    }
    int run = ps[tid] - s;
    for (int i = start; i < end; i++) {
        offs[i] = run;
        cursor[i] = run;
        run += counts[i];
    }
    if (tid == 0) offs[R] = ps[1023];
}

// scatter edges into CSR order; meta = {src, e, bits(tcross[dst]+s_op[src]), 0}.
__global__ void k_scatter(const int* __restrict__ edst, const int* __restrict__ esrc,
                          const float* __restrict__ s_op, const float* __restrict__ tcross,
                          int* __restrict__ cursor, int4* __restrict__ meta, int E) {
    int i = blockIdx.x * blockDim.x + threadIdx.x;
    int n = gridDim.x * blockDim.x;
    for (int e = i; e < E; e += n) {
        int dd = edst[e], ss = esrc[e];
        float sb = tcross[dd] + s_op[ss];
        int pos = atomicAdd(&cursor[dd], 1);
        meta[pos] = make_int4(ss, e, __float_as_int(sb), 0);
    }
}

// one block per resource; 16 groups of 16 lanes; group g owns edges j = g+16i.
// Per edge: group loads ea row (16 lanes x float4), 4-deep xor-reduce gives
// d = ea·v[192:] in all 16 lanes; p = exp(leaky(sbase + d)); then the group
// gathers the ops row in 3 float4 segments and accumulates p*row.
// Outputs X[r][256] (ops part cols 0..191, ea part cols 192..255) and psum[r].
__global__ void k_gather(const float* __restrict__ ops, const float* __restrict__ ea,
                         const int4* __restrict__ meta, const int* __restrict__ offs,
                         const float* __restrict__ v, float* __restrict__ X,
                         float* __restrict__ psum) {
    int r = blockIdx.x;
    int t = threadIdx.x;
    int g = t >> 4, sub = t & 15;
    int beg = offs[r], end = offs[r + 1], cnt = end - beg;
    float4 vv = *(const float4*)(v + DO + sub * 4);
    __shared__ int4 sm[GCH];
    __shared__ float4 red[16][16][4];
    __shared__ float gps[16];
    float4 accA = {0.f, 0.f, 0.f, 0.f};
    float4 accB0 = {0.f, 0.f, 0.f, 0.f};
    float4 accB1 = {0.f, 0.f, 0.f, 0.f};
    float4 accB2 = {0.f, 0.f, 0.f, 0.f};
    float ps = 0.f;
    for (int base = 0; base < cnt; base += GCH) {
        int n = min(GCH, cnt - base);
        if (t < n) sm[t] = meta[beg + base + t];
        __syncthreads();
#pragma unroll 2
        for (int j = g; j < n; j += 16) {
            int4 m = sm[j];
            const float* rowp = ops + (size_t)m.x * DO + sub * 4;
            float4 r0 = *(const float4*)(rowp);
            float4 r1 = *(const float4*)(rowp + 64);
            float4 r2 = *(const float4*)(rowp + 128);
            float4 rv = *(const float4*)(ea + (size_t)m.y * DE + sub * 4);
            float d = rv.x * vv.x + rv.y * vv.y + rv.z * vv.z + rv.w * vv.w;
            d += __shfl_xor(d, 1, 64);
            d += __shfl_xor(d, 2, 64);
            d += __shfl_xor(d, 4, 64);
            d += __shfl_xor(d, 8, 64);
            float sc = __int_as_float(m.z) + d;
            float p = expf(sc >= 0.f ? sc : 0.2f * sc);
            ps += p;
            accA.x += p * rv.x; accA.y += p * rv.y;
            accA.z += p * rv.z; accA.w += p * rv.w;
            accB0.x += p * r0.x; accB0.y += p * r0.y;
            accB0.z += p * r0.z; accB0.w += p * r0.w;
            accB1.x += p * r1.x; accB1.y += p * r1.y;
            accB1.z += p * r1.z; accB1.w += p * r1.w;
            accB2.x += p * r2.x; accB2.y += p * r2.y;
            accB2.z += p * r2.z; accB2.w += p * r2.w;
        }
        __syncthreads();
    }
    red[g][sub][0] = accB0;
    red[g][sub][1] = accB1;
    red[g][sub][2] = accB2;
    red[g][sub][3] = accA;
    if (sub == 0) gps[g] = ps;
    __syncthreads();
    if (t < 64) {
        int su = t & 15, q = t >> 4;
        float4 s = red[0][su][q];
        for (int gg = 1; gg < 16; gg++) {
            float4 a = red[gg][su][q];
            s.x += a.x; s.y += a.y; s.z += a.z; s.w += a.w;
        }
        ((float4*)(X + (size_t)r * EMB))[t] = s;  // col group t covers cols 4t..4t+3
        if (t == 0) {
            float qq = 0.f;
            for (int gg = 0; gg < 16; gg++) qq += gps[gg];
            psum[r] = qq;
        }
    }
}

// S = sum(p_self) + sum(psum)
__global__ void k_sum(const float* __restrict__ p_self, const float* __restrict__ psum,
                      int R, float* __restrict__ S) {
    __shared__ float fs[1024];
    int t = threadIdx.x;
    float fv = 0.f;
    for (int i = t; i < R; i += 1024) fv += p_self[i] + psum[i];
    fs[t] = fv;
    __syncthreads();
    for (int off = 512; off > 0; off >>= 1) {
        if (t < off) fs[t] += fs[t + off];
        __syncthreads();
    }
    if (t == 0) *S = fs[0];
}

// out[r][c] = elu( (p_self[r]*h[r][c] + sum_j wT[j][c]*X[r][j]) / S )
__global__ void k_final(const float* __restrict__ X, const float* __restrict__ wT,
                        const float* __restrict__ h, const float* __restrict__ p_self,
                        const float* __restrict__ Sp, float* __restrict__ out, int R) {
    __shared__ float xl[FRPB][EMB];
    __shared__ float ps[FRPB];
    int r0 = blockIdx.x * FRPB;
    int t = threadIdx.x;
    for (int idx = t; idx < FRPB * EMB / 4; idx += 256) {
        int rr = idx >> 6;
        float4 val = (r0 + rr < R) ? ((const float4*)(X + (size_t)r0 * EMB))[idx]
                                   : make_float4(0.f, 0.f, 0.f, 0.f);
        ((float4*)xl)[idx] = val;
    }
    for (int i = t; i < FRPB; i += 256) ps[i] = (r0 + i < R) ? p_self[r0 + i] : 0.f;
    __syncthreads();
    float acc[FRPB];
#pragma unroll
    for (int rr = 0; rr < FRPB; rr++) acc[rr] = 0.f;
    int c = t;
    for (int j = 0; j < EMB; j += 4) {
        float w0 = wT[(j + 0) * EMB + c];
        float w1 = wT[(j + 1) * EMB + c];
        float w2 = wT[(j + 2) * EMB + c];
        float w3 = wT[(j + 3) * EMB + c];
#pragma unroll
        for (int rr = 0; rr < FRPB; rr++) {
            float4 xv = *(const float4*)&xl[rr][j];
            acc[rr] += xv.x * w0 + xv.y * w1 + xv.z * w2 + xv.w * w3;
        }
    }
    float inv = 1.f / (*Sp);
#pragma unroll
    for (int rr = 0; rr < FRPB; rr++) {
        int r = r0 + rr;
        if (r < R) {
            float val = (ps[rr] * h[(size_t)r * EMB + c] + acc[rr]) * inv;
            out[(size_t)r * EMB + c] = val > 0.f ? val : expm1f(val);
        }
    }
}

extern "C" void kernel_launch(void* const* d_in, const int* in_sizes, int n_in,
                              void* d_out, int out_size, void* d_ws, size_t ws_size,
                              hipStream_t stream) {
    const float* resources = (const float*)d_in[0];
    const float* operations = (const float*)d_in[1];
    const float* edge_attr = (const float*)d_in[2];
    const float* W_self = (const float*)d_in[3];
    const float* W_op = (const float*)d_in[4];
    const float* a_self = (const float*)d_in[5];
    const float* a_op = (const float*)d_in[6];
    const int* edge_src = (const int*)d_in[7];
    const int* edge_dst = (const int*)d_in[8];
    float* out = (float*)d_out;

    const int R = in_sizes[0] / DR;
    const int O = in_sizes[1] / DO;
    const int E = in_sizes[2] / DE;

    // workspace carve — counts and v first so one memset zeroes both
    int* counts = (int*)d_ws;                 // R
    float* v = (float*)(counts + R);          // 256
    float* wsT = v + EMB;                     // 128*256
    float* wT = wsT + DR * EMB;               // 256*256
    float* h = wT + EMB * EMB;                // R*256
    float* X = h + (size_t)R * EMB;           // R*256
    float* tcross = X + (size_t)R * EMB;      // R
    float* p_self = tcross + R;               // R
    float* psum = p_self + R;                 // R
    float* s_op = psum + R;                   // O
    float* S = s_op + O;                      // 1
    int* offs = (int*)(S + 1);                // R+1
    int* cursor = offs + R + 1;               // R
    int4* meta = (int4*)(cursor + R);         // E (16B each)

    hipMemsetAsync(d_ws, 0, (size_t)(R + EMB) * sizeof(float), stream);

    const int NBH = (R + RPB - 1) / RPB;
    const int NBS = (O + 3) / 4;

    k_prep<<<416 + HB, 256, 0, stream>>>(wsT, wT, v, W_self, W_op, a_op, edge_dst,
                                         counts, E);
    k_hs<<<NBH + NBS, 256, 0, stream>>>(resources, wsT, a_self, a_op, operations, v,
                                        h, tcross, p_self, s_op, R, O, NBH);
    k_scan<<<1, 1024, 0, stream>>>(counts, offs, cursor, R);
    k_scatter<<<1024, 256, 0, stream>>>(edge_dst, edge_src, s_op, tcross, cursor, meta, E);
    k_gather<<<R, 256, 0, stream>>>(operations, edge_attr, meta, offs, v, X, psum);
    k_sum<<<1, 1024, 0, stream>>>(p_self, psum, R, S);
    k_final<<<(R + FRPB - 1) / FRPB, 256, 0, stream>>>(X, wT, h, p_self, S, out, R);
}

// Round 6
// 273.729 us; speedup vs baseline: 1.1212x; 1.1212x over previous
//
#include <hip/hip_runtime.h>
#include <math.h>

#define EMB 256
#define DR  128   // resource feature dim
#define DO  192   // operation feature dim
#define DE  64    // edge_attr dim
#define RPB 8     // resources per block in k_h part
#define FRPB 16   // resources per block in k_final (32 spilled acc -> scratch, R5 post-mortem)
#define KV_CH 8   // k-rows per block in the v part of k_prep
#define HB 256    // histogram blocks in k_prep
#define GCH 64    // edges staged per chunk in k_gather

__device__ __forceinline__ float leaky(float x) { return x >= 0.f ? x : 0.2f * x; }

// Fused prep: blocks [0,128) transpose W_self -> wsT [128][256];
// blocks [128,384) transpose W_op -> wT [256][256];
// blocks [384,416) accumulate v[j] = sum_k W_op[k][j]*a_op[256+k] (v pre-zeroed);
// blocks [416,416+HB) histogram edge_dst into counts (pre-zeroed).
__global__ void k_prep(float* __restrict__ wsT, float* __restrict__ wT,
                       float* __restrict__ v, const float* __restrict__ W_self,
                       const float* __restrict__ W_op, const float* __restrict__ a_op,
                       const int* __restrict__ edst, int* __restrict__ counts, int E) {
    int b = blockIdx.x, t = threadIdx.x;
    if (b < 128) {
        int i = b * 256 + t;
        int k = i & 255, j = i >> 8;    // wsT[j*256+k] = W_self[k*128+j]
        wsT[i] = W_self[k * DR + j];
    } else if (b < 384) {
        int i = (b - 128) * 256 + t;
        int k = i & 255, j = i >> 8;    // wT[j*256+k] = W_op[k*256+j]
        wT[i] = W_op[(size_t)k * EMB + j];
    } else if (b < 416) {
        int k0 = (b - 384) * KV_CH;
        float acc = 0.f;
#pragma unroll
        for (int u = 0; u < KV_CH; u++)
            acc += W_op[(size_t)(k0 + u) * EMB + t] * a_op[EMB + k0 + u];
        atomicAdd(&v[t], acc);
    } else {
        int i = (b - 416) * 256 + t;
        int n = HB * 256;
        for (int e = i; e < E; e += n) atomicAdd(&counts[edst[e]], 1);
    }
}

// Fused: blocks [0,NBH): h[r] = resources[r] @ wsT, plus per-resource scores
// tcross[r] = h[r]·a_op[:256], p_self[r] = exp(leaky(h[r]·(a_self[:256]+a_self[256:]))).
// blocks [NBH, ...): s_op[o] = operations[o][0:192]·v[0:192].
__global__ void k_hs(const float* __restrict__ res, const float* __restrict__ wsT,
                     const float* __restrict__ a_self, const float* __restrict__ a_op,
                     const float* __restrict__ ops, const float* __restrict__ v,
                     float* __restrict__ h, float* __restrict__ tcross,
                     float* __restrict__ p_self, float* __restrict__ s_op,
                     int R, int O, int NBH) {
    if ((int)blockIdx.x < NBH) {
        __shared__ float rrow[RPB][DR];
        __shared__ float hred[RPB][4][2];
        int r0 = blockIdx.x * RPB;
        int k = threadIdx.x;
        int w = k >> 6, l = k & 63;
        for (int i = k; i < RPB * DR; i += EMB) {
            int rr = i / DR, j = i % DR;
            rrow[rr][j] = (r0 + rr < R) ? res[(size_t)(r0 + rr) * DR + j] : 0.f;
        }
        __syncthreads();
        float acc[RPB];
#pragma unroll
        for (int rr = 0; rr < RPB; rr++) acc[rr] = 0.f;
        for (int j = 0; j < DR; j++) {
            float wv = wsT[j * EMB + k];
#pragma unroll
            for (int rr = 0; rr < RPB; rr++) acc[rr] += rrow[rr][j] * wv;
        }
        float as_ = a_self[k] + a_self[EMB + k];
        float ao_ = a_op[k];
#pragma unroll
        for (int rr = 0; rr < RPB; rr++) {
            if (r0 + rr < R) h[(size_t)(r0 + rr) * EMB + k] = acc[rr];
            float s1 = acc[rr] * as_;
            float s2 = acc[rr] * ao_;
            for (int m = 1; m < 64; m <<= 1) {
                s1 += __shfl_xor(s1, m, 64);
                s2 += __shfl_xor(s2, m, 64);
            }
            if (l == 0) { hred[rr][w][0] = s1; hred[rr][w][1] = s2; }
        }
        __syncthreads();
        if (k < RPB) {
            int r = r0 + k;
            if (r < R) {
                float a1 = hred[k][0][0] + hred[k][1][0] + hred[k][2][0] + hred[k][3][0];
                float a2 = hred[k][0][1] + hred[k][1][1] + hred[k][2][1] + hred[k][3][1];
                p_self[r] = expf(leaky(a1));
                tcross[r] = a2;
            }
        }
    } else {
        __shared__ float vv[DO];
        int tid = threadIdx.x;
        if (tid < DO) vv[tid] = v[tid];
        __syncthreads();
        int wave = tid >> 6, lane = tid & 63;
        int o = (blockIdx.x - NBH) * 4 + wave;
        if (o >= O) return;
        const float* row = ops + (size_t)o * DO;
        float acc = row[lane] * vv[lane] + row[lane + 64] * vv[lane + 64] +
                    row[lane + 128] * vv[lane + 128];
        for (int m = 1; m < 64; m <<= 1) acc += __shfl_xor(acc, m, 64);
        if (lane == 0) s_op[o] = acc;
    }
}

// single block: exclusive scan of counts -> offs (R+1) and cursor copy.
__global__ void k_scan(const int* __restrict__ counts, int* __restrict__ offs,
                       int* __restrict__ cursor, int R) {
    __shared__ int ps[1024];
    int tid = threadIdx.x;
    int chunk = (R + 1023) >> 10;
    int start = tid * chunk;
    int end = min(start + chunk, R);
    int s = 0;
    for (int i = start; i < end; i++) s += counts[i];
    ps[tid] = s;
    __syncthreads();
    for (int off = 1; off < 1024; off <<= 1) {
        int add = (tid >= off) ? ps[tid - off] : 0;
        __syncthreads();
        ps[tid] += add;
        __syncthreads();
    }
    int run = ps[tid] - s;
    for (int i = start; i < end; i++) {
        offs[i] = run;
        cursor[i] = run;
        run += counts[i];
    }
    if (tid == 0) offs[R] = ps[1023];
}

// scatter edges into CSR order; meta = {src, e} (8B).
__global__ void k_scatter(const int* __restrict__ edst, const int* __restrict__ esrc,
                          int* __restrict__ cursor, int2* __restrict__ meta, int E) {
    int i = blockIdx.x * blockDim.x + threadIdx.x;
    int n = gridDim.x * blockDim.x;
    for (int e = i; e < E; e += n) {
        int pos = atomicAdd(&cursor[edst[e]], 1);
        meta[pos] = make_int2(esrc[e], e);
    }
}

// one block per resource; 16 groups of 16 lanes; group g owns edges j = g+16i.
// Chunk staging also precomputes ssb[j] = tcross[r] + s_op[src_j] (L2 gather, off
// the critical path). Per edge: group loads ea row (16 lanes x float4), 4-deep
// xor-reduce gives d = ea·v[192:]; p = exp(leaky(ssb + d)); group gathers the
// ops row in 3 float4 segments and accumulates p*row. Outputs X[r][256], psum[r].
__global__ void k_gather(const float* __restrict__ ops, const float* __restrict__ ea,
                         const int2* __restrict__ meta, const int* __restrict__ offs,
                         const float* __restrict__ v, const float* __restrict__ s_op,
                         const float* __restrict__ tcross, float* __restrict__ X,
                         float* __restrict__ psum) {
    int r = blockIdx.x;
    int t = threadIdx.x;
    int g = t >> 4, sub = t & 15;
    int beg = offs[r], end = offs[r + 1], cnt = end - beg;
    float4 vv = *(const float4*)(v + DO + sub * 4);
    float tc = tcross[r];
    __shared__ int2 sm[GCH];
    __shared__ float ssb[GCH];
    __shared__ float4 red[16][16][4];
    __shared__ float gps[16];
    float4 accA = {0.f, 0.f, 0.f, 0.f};
    float4 accB0 = {0.f, 0.f, 0.f, 0.f};
    float4 accB1 = {0.f, 0.f, 0.f, 0.f};
    float4 accB2 = {0.f, 0.f, 0.f, 0.f};
    float ps = 0.f;
    for (int base = 0; base < cnt; base += GCH) {
        int n = min(GCH, cnt - base);
        if (t < n) {
            int2 m = meta[beg + base + t];
            sm[t] = m;
            ssb[t] = tc + s_op[m.x];
        }
        __syncthreads();
#pragma unroll 2
        for (int j = g; j < n; j += 16) {
            int2 m = sm[j];
            const float* rowp = ops + (size_t)m.x * DO + sub * 4;
            float4 r0 = *(const float4*)(rowp);
            float4 r1 = *(const float4*)(rowp + 64);
            float4 r2 = *(const float4*)(rowp + 128);
            float4 rv = *(const float4*)(ea + (size_t)m.y * DE + sub * 4);
            float d = rv.x * vv.x + rv.y * vv.y + rv.z * vv.z + rv.w * vv.w;
            d += __shfl_xor(d, 1, 64);
            d += __shfl_xor(d, 2, 64);
            d += __shfl_xor(d, 4, 64);
            d += __shfl_xor(d, 8, 64);
            float sc = ssb[j] + d;
            float p = expf(sc >= 0.f ? sc : 0.2f * sc);
            ps += p;
            accA.x += p * rv.x; accA.y += p * rv.y;
            accA.z += p * rv.z; accA.w += p * rv.w;
            accB0.x += p * r0.x; accB0.y += p * r0.y;
            accB0.z += p * r0.z; accB0.w += p * r0.w;
            accB1.x += p * r1.x; accB1.y += p * r1.y;
            accB1.z += p * r1.z; accB1.w += p * r1.w;
            accB2.x += p * r2.x; accB2.y += p * r2.y;
            accB2.z += p * r2.z; accB2.w += p * r2.w;
        }
        __syncthreads();
    }
    red[g][sub][0] = accB0;
    red[g][sub][1] = accB1;
    red[g][sub][2] = accB2;
    red[g][sub][3] = accA;
    if (sub == 0) gps[g] = ps;
    __syncthreads();
    if (t < 64) {
        int su = t & 15, q = t >> 4;
        float4 s = red[0][su][q];
        for (int gg = 1; gg < 16; gg++) {
            float4 a = red[gg][su][q];
            s.x += a.x; s.y += a.y; s.z += a.z; s.w += a.w;
        }
        ((float4*)(X + (size_t)r * EMB))[t] = s;  // col group t covers cols 4t..4t+3
        if (t == 0) {
            float qq = 0.f;
            for (int gg = 0; gg < 16; gg++) qq += gps[gg];
            psum[r] = qq;
        }
    }
}

// S = sum(p_self) + sum(psum)
__global__ void k_sum(const float* __restrict__ p_self, const float* __restrict__ psum,
                      int R, float* __restrict__ S) {
    __shared__ float fs[1024];
    int t = threadIdx.x;
    float fv = 0.f;
    for (int i = t; i < R; i += 1024) fv += p_self[i] + psum[i];
    fs[t] = fv;
    __syncthreads();
    for (int off = 512; off > 0; off >>= 1) {
        if (t < off) fs[t] += fs[t + off];
        __syncthreads();
    }
    if (t == 0) *S = fs[0];
}

// out[r][c] = elu( (p_self[r]*h[r][c] + sum_j wT[j][c]*X[r][j]) / S )
__global__ void k_final(const float* __restrict__ X, const float* __restrict__ wT,
                        const float* __restrict__ h, const float* __restrict__ p_self,
                        const float* __restrict__ Sp, float* __restrict__ out, int R) {
    __shared__ float xl[FRPB][EMB];
    __shared__ float ps[FRPB];
    int r0 = blockIdx.x * FRPB;
    int t = threadIdx.x;
    for (int idx = t; idx < FRPB * EMB / 4; idx += 256) {
        int rr = idx >> 6;  // EMB/4 = 64 float4 per row
        float4 val = (r0 + rr < R) ? ((const float4*)(X + (size_t)r0 * EMB))[idx]
                                   : make_float4(0.f, 0.f, 0.f, 0.f);
        ((float4*)xl)[idx] = val;
    }
    if (t < FRPB) ps[t] = (r0 + t < R) ? p_self[r0 + t] : 0.f;
    __syncthreads();
    float acc[FRPB];
#pragma unroll
    for (int rr = 0; rr < FRPB; rr++) acc[rr] = 0.f;
    int c = t;
    for (int j = 0; j < EMB; j += 4) {
        float w0 = wT[(j + 0) * EMB + c];
        float w1 = wT[(j + 1) * EMB + c];
        float w2 = wT[(j + 2) * EMB + c];
        float w3 = wT[(j + 3) * EMB + c];
#pragma unroll
        for (int rr = 0; rr < FRPB; rr++) {
            float4 xv = *(const float4*)&xl[rr][j];
            acc[rr] += xv.x * w0 + xv.y * w1 + xv.z * w2 + xv.w * w3;
        }
    }
    float inv = 1.f / (*Sp);
#pragma unroll
    for (int rr = 0; rr < FRPB; rr++) {
        int r = r0 + rr;
        if (r < R) {
            float val = (ps[rr] * h[(size_t)r * EMB + c] + acc[rr]) * inv;
            out[(size_t)r * EMB + c] = val > 0.f ? val : expm1f(val);
        }
    }
}

extern "C" void kernel_launch(void* const* d_in, const int* in_sizes, int n_in,
                              void* d_out, int out_size, void* d_ws, size_t ws_size,
                              hipStream_t stream) {
    const float* resources = (const float*)d_in[0];
    const float* operations = (const float*)d_in[1];
    const float* edge_attr = (const float*)d_in[2];
    const float* W_self = (const float*)d_in[3];
    const float* W_op = (const float*)d_in[4];
    const float* a_self = (const float*)d_in[5];
    const float* a_op = (const float*)d_in[6];
    const int* edge_src = (const int*)d_in[7];
    const int* edge_dst = (const int*)d_in[8];
    float* out = (float*)d_out;

    const int R = in_sizes[0] / DR;
    const int O = in_sizes[1] / DO;
    const int E = in_sizes[2] / DE;

    // workspace carve — counts and v first so one memset zeroes both
    int* counts = (int*)d_ws;                 // R
    float* v = (float*)(counts + R);          // 256
    float* wsT = v + EMB;                     // 128*256
    float* wT = wsT + DR * EMB;               // 256*256
    float* h = wT + EMB * EMB;                // R*256
    float* X = h + (size_t)R * EMB;           // R*256
    float* tcross = X + (size_t)R * EMB;      // R
    float* p_self = tcross + R;               // R
    float* psum = p_self + R;                 // R
    float* s_op = psum + R;                   // O
    float* S = s_op + O;                      // 1
    int* offs = (int*)(S + 1);                // R+1
    int* cursor = offs + R + 1;               // R
    int2* meta = (int2*)(cursor + R);         // E (8B each)

    hipMemsetAsync(d_ws, 0, (size_t)(R + EMB) * sizeof(float), stream);

    const int NBH = (R + RPB - 1) / RPB;
    const int NBS = (O + 3) / 4;

    k_prep<<<416 + HB, 256, 0, stream>>>(wsT, wT, v, W_self, W_op, a_op, edge_dst,
                                         counts, E);
    k_hs<<<NBH + NBS, 256, 0, stream>>>(resources, wsT, a_self, a_op, operations, v,
                                        h, tcross, p_self, s_op, R, O, NBH);
    k_scan<<<1, 1024, 0, stream>>>(counts, offs, cursor, R);
    k_scatter<<<1024, 256, 0, stream>>>(edge_dst, edge_src, cursor, meta, E);
    k_gather<<<R, 256, 0, stream>>>(operations, edge_attr, meta, offs, v, s_op, tcross,
                                    X, psum);
    k_sum<<<1, 1024, 0, stream>>>(p_self, psum, R, S);
    k_final<<<(R + FRPB - 1) / FRPB, 256, 0, stream>>>(X, wT, h, p_self, S, out, R);
}